// Round 3
// baseline (476.706 us; speedup 1.0000x reference)
//
#include <hip/hip_runtime.h>

// VanillaVectorQuantizer: N=131072 positions (B=32,H=64,W=64), D=64, K=512.
// enc layout [B, D, H, W]: element (b,d,p) at b*D*HW + d*HW + p, p=h*64+w.
//
// Numerics are an EXACT emulation of the numpy fp32 reference chain
// (verified bitwise in round 2, absmax == 0):
//   - M_k: ascending-d fp32 FMA chain (== BLAS sgemm microkernel)
//   - sq_x: numpy pairwise_sum(n=64): 8 stride-8 accumulators of pre-rounded
//     squares (mul then add, NO fma), combine ((r0+r1)+(r2+r3))+((r4+r5)+(r6+r7))
//   - sq_e: sequential d-sum of pre-rounded squares (NO fma)
//   - dist: fl(fl(sq_x - fl(2*M)) + sq_e), contraction off
//   - strict '<' ascending k == np.argmin first-index tie-break
// DO NOT alter any of these chains.
//
// Perf structure (round 3): 4 waves/block over 128 positions; waves 0-1 scan
// k in [0,256), waves 2-3 scan [256,512) (kbase wave-uniform -> cb/sqe stay
// scalar loads). Combine via LDS; disjoint k-ranges make ties resolve to the
// lower half automatically. x[64] pinned in VGPRs via empty asm touch (the
// round-2 compiler sank the loads into the K-loop: VGPR_Count=48, 3.7x floor).

#pragma clang fp contract(off)

#define VQ_D 64
#define VQ_K 512
#define VQ_HW 4096
#define VQ_N 131072

__global__ void vq_sqe_kernel(const float* __restrict__ cb,
                              float* __restrict__ sqe) {
    const int k = threadIdx.x;  // 512 threads, one block
    float s = cb[k] * cb[k];    // d = 0 (square rounded, then added: no fma)
    for (int d = 1; d < VQ_D; ++d) {
        const float v = cb[d * VQ_K + k];
        const float sq = v * v;  // contract(off): rounds the square
        s = s + sq;              // then rounds the add (numpy axis-0 reduce)
    }
    sqe[k] = s;
}

__global__ __launch_bounds__(256, 4) void vq_main_kernel(
    const float* __restrict__ enc, const float* __restrict__ cb,
    const float* __restrict__ sqe, float* __restrict__ out) {
    __shared__ float sbest[256];
    __shared__ int sbk[256];

    const int tid = threadIdx.x;
    const int wid = tid >> 6;          // 0..3
    const int lane = tid & 63;
    const int half = wid >> 1;         // 0: k in [0,256), 1: k in [256,512)
    const int pidx = ((wid & 1) << 6) | lane;         // 0..127 within block
    const int pos = blockIdx.x * 128 + pidx;          // position id
    const int b = pos >> 12;           // position / (H*W)
    const int r = pos & (VQ_HW - 1);   // h*64+w
    const float* xp = enc + (size_t)b * (VQ_D * VQ_HW) + r;

    // Load this position's vector into registers (coalesced across lanes).
    float x[VQ_D];
#pragma unroll
    for (int d = 0; d < VQ_D; ++d) x[d] = xp[(size_t)d * VQ_HW];
    // Pin x in VGPRs: forbid the compiler from sinking/re-materializing the
    // loads inside the K-loop (round-2 codegen defect: VGPR=48, 32x reload).
#pragma unroll
    for (int d = 0; d < VQ_D; ++d) asm volatile("" : "+v"(x[d]));

    // sq_x: exact emulation of numpy pairwise_sum over fl(x*x), n=64.
    float pr[8];
#pragma unroll
    for (int j = 0; j < 8; ++j) pr[j] = x[j] * x[j];
#pragma unroll
    for (int i = 8; i < VQ_D; i += 8) {
#pragma unroll
        for (int j = 0; j < 8; ++j) {
            const float sq = x[i + j] * x[i + j];  // rounded square
            pr[j] = pr[j] + sq;                    // rounded add
        }
    }
    const float sqx = ((pr[0] + pr[1]) + (pr[2] + pr[3])) +
                      ((pr[4] + pr[5]) + (pr[6] + pr[7]));

    float best = 3.402823466e38f;
    int bestk = 0;
    const int kbase = half << 8;  // wave-uniform -> cb/sqe stay scalar loads

    for (int kt = kbase; kt < kbase + 256; kt += 16) {
        float acc[16];
#pragma unroll
        for (int j = 0; j < 16; ++j) acc[j] = 0.f;
#pragma unroll
        for (int d = 0; d < VQ_D; ++d) {
            const float xd = x[d];
#pragma unroll
            for (int j = 0; j < 16; ++j)  // ascending-d FMA chain == sgemm
                acc[j] = fmaf(xd, cb[d * VQ_K + kt + j], acc[j]);
        }
#pragma unroll
        for (int j = 0; j < 16; ++j) {
            const float m2 = 2.0f * acc[j];        // exact (power of 2)
            const float tmp = sqx - m2;            // rounds: fl(sq_x - 2M)
            const float dist = tmp + sqe[kt + j];  // rounds: + sq_e
            if (dist < best) {  // strict '<': first (lowest) index on ties
                best = dist;
                bestk = kt + j;
            }
        }
    }

    // Combine the two k-halves (disjoint ranges: tie -> lower half's k, which
    // the strict '<' below implements since half-0 holds the lower range).
    sbest[tid] = best;
    sbk[tid] = bestk;
    __syncthreads();
    if (half == 0) {
        const float ob = sbest[128 + pidx];
        if (ob < best) {
            best = ob;
            bestk = sbk[128 + pidx];
        }
        sbk[pidx] = bestk;  // publish final index for the half-1 partner
    }
    __syncthreads();
    bestk = sbk[pidx];

    // Gather winning codebook column; each half stores 32 of the 64 d-planes
    // (stores stay 256B-contiguous per wave: 64 consecutive positions).
    float* op = out + (size_t)b * (VQ_D * VQ_HW) + r;
    const int dbase = half << 5;
#pragma unroll
    for (int sd = 0; sd < 32; ++sd) {
        const int d = dbase + sd;
        op[(size_t)d * VQ_HW] = cb[d * VQ_K + bestk];
    }
}

extern "C" void kernel_launch(void* const* d_in, const int* in_sizes, int n_in,
                              void* d_out, int out_size, void* d_ws, size_t ws_size,
                              hipStream_t stream) {
    const float* enc = (const float*)d_in[0];  // [32,64,64,64]
    const float* cb  = (const float*)d_in[1];  // [64,512]
    float* out = (float*)d_out;
    float* sqe = (float*)d_ws;  // 512 floats

    vq_sqe_kernel<<<1, VQ_K, 0, stream>>>(cb, sqe);
    vq_main_kernel<<<VQ_N / 128, 256, 0, stream>>>(enc, cb, sqe, out);
}